// Round 1
// baseline (87.771 us; speedup 1.0000x reference)
//
#include <hip/hip_runtime.h>
#include <math.h>

// Problem constants (B,T,N,D) = (16,100,128,3), fp32 in, fp32 scalar out.
constexpr int B = 16, T = 100, N = 128;
constexpr float MIN_DIST  = 0.05f;
constexpr float MIN_DIST2 = MIN_DIST * MIN_DIST;

constexpr int THREADS     = 256;
constexpr int PEN_BLOCKS  = B * T;                // 1600 — one block per (b,t) slice
constexpr int MISC_BLOCKS = 160;
constexpr int TOTAL_BLOCKS = PEN_BLOCKS + MISC_BLOCKS;

constexpr int WORK_N = B * (T - 1) * N;           // 202752 work dot-products
constexpr int STAB_N = B * 5 * N;                 // 10240 stability norms
constexpr int KE_N   = 2 * B * N;                 // 4096 kinetic terms (t=0 and t=T-1)
constexpr int MISC_TOTAL = WORK_N + STAB_N + KE_N;

// ws float-slot layout (atomic partials, spread to dodge same-address serialization)
constexpr int PEN_SLOTS = 32;   // ws[0..31]
constexpr int WORK_SLOT = 32;   // ws[32..39]
constexpr int STAB_SLOT = 40;   // ws[40..47]
constexpr int KE0_SLOT  = 48;   // ws[48..55]
constexpr int KE1_SLOT  = 56;   // ws[56..63]

__device__ __forceinline__ float wave_sum(float v) {
#pragma unroll
    for (int off = 32; off > 0; off >>= 1) v += __shfl_down(v, off, 64);
    return v;
}

__global__ __launch_bounds__(THREADS) void physics_fused(
    const float* __restrict__ traj, const float* __restrict__ vel,
    const float* __restrict__ frc, float* __restrict__ ws)
{
    __shared__ float4 spos[N];       // padded xyz -> one ds_read_b128 per point
    __shared__ float  red[4][4];     // [value][wave]

    const int tid  = threadIdx.x;
    const int bid  = blockIdx.x;
    const int lane = tid & 63;
    const int wv   = tid >> 6;

    if (bid < PEN_BLOCKS) {
        // ---- penetration term for one (b,t) slice ----
        const float* p = traj + (size_t)bid * (N * 3);
        for (int k = tid; k < N; k += THREADS)
            spos[k] = make_float4(p[k * 3], p[k * 3 + 1], p[k * 3 + 2], 0.f);
        __syncthreads();

        const int i      = tid & (N - 1);          // point owned by this thread
        const int jbase  = (tid >> 7) * (N / 2);   // two half-ranges of j
        const float4 pi  = spos[i];
        float s = 0.f;
#pragma unroll 4
        for (int jj = 0; jj < N / 2; ++jj) {
            const int j = jbase + jj;              // wave-uniform -> LDS broadcast
            const float4 pj = spos[j];
            const float dx = pi.x - pj.x, dy = pi.y - pj.y, dz = pi.z - pj.z;
            const float d2 = dx * dx + dy * dy + dz * dz;
            if (d2 < MIN_DIST2 && j != i)          // sqrt almost never taken
                s += MIN_DIST - sqrtf(d2);
        }
        float w = wave_sum(s);
        if (lane == 0) red[0][wv] = w;
        __syncthreads();
        if (tid == 0) {
            const float tot = red[0][0] + red[0][1] + red[0][2] + red[0][3];
            // ordered pairs counted twice -> *0.5
            atomicAdd(&ws[bid & (PEN_SLOTS - 1)], 0.5f * tot);
        }
    } else {
        // ---- work / stability / kinetic sums, grid-stride ----
        float sw = 0.f, ss = 0.f, k0 = 0.f, k1 = 0.f;
        const int stride = MISC_BLOCKS * THREADS;
        for (int idx = (bid - PEN_BLOCKS) * THREADS + tid; idx < MISC_TOTAL; idx += stride) {
            if (idx < WORK_N) {
                const int n  = idx & (N - 1);
                const int bt = idx >> 7;           // b*(T-1)+t
                const int t  = bt % (T - 1);
                const int b  = bt / (T - 1);
                const size_t o = ((size_t)((b * T + t) * N + n)) * 3;
                const float fx = frc[o], fy = frc[o + 1], fz = frc[o + 2];
                const float dx = traj[o + 3 * N]     - traj[o];
                const float dy = traj[o + 3 * N + 1] - traj[o + 1];
                const float dz = traj[o + 3 * N + 2] - traj[o + 2];
                sw += fx * dx + fy * dy + fz * dz;
            } else if (idx < WORK_N + STAB_N) {
                const int s2 = idx - WORK_N;
                const int n  = s2 & (N - 1);
                const int bt = s2 >> 7;            // b*5+tt
                const int tt = bt % 5, b = bt / 5;
                const size_t o = ((size_t)((b * T + (T - 5 + tt)) * N + n)) * 3;
                const float vx = vel[o], vy = vel[o + 1], vz = vel[o + 2];
                ss += sqrtf(vx * vx + vy * vy + vz * vz);
            } else {
                const int s2 = idx - WORK_N - STAB_N;   // [0,4096)
                const int n  = s2 & (N - 1);
                const int b  = (s2 >> 7) & (B - 1);
                const int which = s2 >> 11;             // 0 -> t=0, 1 -> t=T-1
                const size_t o = ((size_t)((b * T + which * (T - 1)) * N + n)) * 3;
                const float vx = vel[o], vy = vel[o + 1], vz = vel[o + 2];
                const float ke = vx * vx + vy * vy + vz * vz;
                if (which) k1 += ke; else k0 += ke;
            }
        }
        float vals[4] = {sw, ss, k0, k1};
#pragma unroll
        for (int v = 0; v < 4; ++v) {
            float w = wave_sum(vals[v]);
            if (lane == 0) red[v][wv] = w;
        }
        __syncthreads();
        if (tid == 0) {
            const int slot = bid & 7;
            atomicAdd(&ws[WORK_SLOT + slot], red[0][0] + red[0][1] + red[0][2] + red[0][3]);
            atomicAdd(&ws[STAB_SLOT + slot], red[1][0] + red[1][1] + red[1][2] + red[1][3]);
            atomicAdd(&ws[KE0_SLOT  + slot], red[2][0] + red[2][1] + red[2][2] + red[2][3]);
            atomicAdd(&ws[KE1_SLOT  + slot], red[3][0] + red[3][1] + red[3][2] + red[3][3]);
        }
    }
}

__global__ void physics_finalize(const float* __restrict__ ws, float* __restrict__ out) {
    const int lane = threadIdx.x;          // 64 threads, one wave
    const float v = ws[lane];
    float pen = 0.f, wk = 0.f, st = 0.f, k0 = 0.f, k1 = 0.f;
    for (int k = 0; k < 64; ++k) {
        const float x = __shfl(v, k, 64);
        if (k < 32)      pen += x;
        else if (k < 40) wk  += x;
        else if (k < 48) st  += x;
        else if (k < 56) k0  += x;
        else             k1  += x;
    }
    if (lane == 0) {
        const float pen_loss  = pen / (float)((long long)B * T * (N * (N - 1) / 2));
        const float stab_loss = st / (float)STAB_N;
        const float ke_s = 0.5f * k0 / (float)(B * N);
        const float ke_e = 0.5f * k1 / (float)(B * N);
        const float work = wk / (float)WORK_N;
        out[0] = 10.0f * pen_loss + stab_loss + 0.1f * fabsf(ke_e - ke_s - work);
    }
}

extern "C" void kernel_launch(void* const* d_in, const int* in_sizes, int n_in,
                              void* d_out, int out_size, void* d_ws, size_t ws_size,
                              hipStream_t stream) {
    const float* traj = (const float*)d_in[0];
    const float* vel  = (const float*)d_in[1];
    const float* frc  = (const float*)d_in[2];
    float* out = (float*)d_out;
    float* ws  = (float*)d_ws;

    hipMemsetAsync(ws, 0, 64 * sizeof(float), stream);
    physics_fused<<<TOTAL_BLOCKS, THREADS, 0, stream>>>(traj, vel, frc, ws);
    physics_finalize<<<1, 64, 0, stream>>>(ws, out);
}

// Round 2
// 81.861 us; speedup vs baseline: 1.0722x; 1.0722x over previous
//
#include <hip/hip_runtime.h>
#include <math.h>

// (B,T,N,D) = (16,100,128,3), fp32 in, fp32 scalar out.
constexpr int B = 16, T = 100, N = 128;
constexpr float MIN_DIST  = 0.05f;
constexpr float MIN_DIST2 = MIN_DIST * MIN_DIST;

constexpr int THREADS      = 256;
constexpr int PEN_BLOCKS   = B * T;               // 1600 — one block per (b,t) slice
constexpr int MISC_BLOCKS  = 160;
constexpr int TOTAL_BLOCKS = PEN_BLOCKS + MISC_BLOCKS;

constexpr int WORK_N = B * (T - 1) * N;           // 202752
constexpr int STAB_N = B * 5 * N;                 // 10240
constexpr int KE_N   = 2 * B * N;                 // 4096
constexpr int MISC_TOTAL = WORK_N + STAB_N + KE_N;

// ws layout (all slots written every call -> no zero-init node needed):
// [0,1600)      pen partial per pen block
// [1600,1760)   work partial per misc block
// [1760,1920)   stability partial per misc block
// [1920,2080)   ke(t=0) partial per misc block
// [2080,2240)   ke(t=T-1) partial per misc block
constexpr int WORK_OFF = 1600, STAB_OFF = 1760, KE0_OFF = 1920, KE1_OFF = 2080;

__device__ __forceinline__ float wave_sum(float v) {
#pragma unroll
    for (int off = 32; off > 0; off >>= 1) v += __shfl_down(v, off, 64);
    return v;
}

__global__ __launch_bounds__(THREADS) void physics_fused(
    const float* __restrict__ traj, const float* __restrict__ vel,
    const float* __restrict__ frc, float* __restrict__ ws)
{
    __shared__ float4 spos[N];     // padded xyz -> single b128 LDS access per point
    __shared__ float  red[4][4];   // [value][wave]

    const int tid  = threadIdx.x;
    const int bid  = blockIdx.x;
    const int lane = tid & 63;
    const int wv   = tid >> 6;

    if (bid < PEN_BLOCKS) {
        // ---- penetration term for one (b,t) slice ----
        const float* p = traj + (size_t)bid * (N * 3);
        for (int k = tid; k < N; k += THREADS)
            spos[k] = make_float4(p[k * 3], p[k * 3 + 1], p[k * 3 + 2], 0.f);
        __syncthreads();

        const int i     = tid & (N - 1);
        const int jbase = (tid >> 7) * (N / 2);
        const float4 pi = spos[i];
        float s = 0.f;
#pragma unroll 4
        for (int jj = 0; jj < N / 2; ++jj) {
            const int j = jbase + jj;              // wave-uniform -> LDS broadcast
            const float4 pj = spos[j];
            const float dx = pi.x - pj.x, dy = pi.y - pj.y, dz = pi.z - pj.z;
            const float d2 = dx * dx + dy * dy + dz * dz;
            if (d2 < MIN_DIST2 && j != i)          // sqrt almost never taken
                s += MIN_DIST - sqrtf(d2);
        }
        float w = wave_sum(s);
        if (lane == 0) red[0][wv] = w;
        __syncthreads();
        if (tid == 0)
            ws[bid] = 0.5f * (red[0][0] + red[0][1] + red[0][2] + red[0][3]);
    } else {
        // ---- work / stability / kinetic sums, grid-stride ----
        const int mb = bid - PEN_BLOCKS;
        float sw = 0.f, ss = 0.f, k0 = 0.f, k1 = 0.f;
        const int stride = MISC_BLOCKS * THREADS;
        for (int idx = mb * THREADS + tid; idx < MISC_TOTAL; idx += stride) {
            if (idx < WORK_N) {
                const int n  = idx & (N - 1);
                const int bt = idx >> 7;           // b*(T-1)+t
                const int t  = bt % (T - 1);
                const int b  = bt / (T - 1);
                const size_t o = ((size_t)((b * T + t) * N + n)) * 3;
                const float fx = frc[o], fy = frc[o + 1], fz = frc[o + 2];
                const float dx = traj[o + 3 * N]     - traj[o];
                const float dy = traj[o + 3 * N + 1] - traj[o + 1];
                const float dz = traj[o + 3 * N + 2] - traj[o + 2];
                sw += fx * dx + fy * dy + fz * dz;
            } else if (idx < WORK_N + STAB_N) {
                const int s2 = idx - WORK_N;
                const int n  = s2 & (N - 1);
                const int bt = s2 >> 7;            // b*5+tt
                const int tt = bt % 5, b = bt / 5;
                const size_t o = ((size_t)((b * T + (T - 5 + tt)) * N + n)) * 3;
                const float vx = vel[o], vy = vel[o + 1], vz = vel[o + 2];
                ss += sqrtf(vx * vx + vy * vy + vz * vz);
            } else {
                const int s2 = idx - WORK_N - STAB_N;   // [0,4096)
                const int n  = s2 & (N - 1);
                const int b  = (s2 >> 7) & (B - 1);
                const int which = s2 >> 11;             // 0 -> t=0, 1 -> t=T-1
                const size_t o = ((size_t)((b * T + which * (T - 1)) * N + n)) * 3;
                const float vx = vel[o], vy = vel[o + 1], vz = vel[o + 2];
                const float ke = vx * vx + vy * vy + vz * vz;
                if (which) k1 += ke; else k0 += ke;
            }
        }
        float vals[4] = {sw, ss, k0, k1};
#pragma unroll
        for (int v = 0; v < 4; ++v) {
            float w = wave_sum(vals[v]);
            if (lane == 0) red[v][wv] = w;
        }
        __syncthreads();
        if (tid == 0) {
            ws[WORK_OFF + mb] = red[0][0] + red[0][1] + red[0][2] + red[0][3];
            ws[STAB_OFF + mb] = red[1][0] + red[1][1] + red[1][2] + red[1][3];
            ws[KE0_OFF  + mb] = red[2][0] + red[2][1] + red[2][2] + red[2][3];
            ws[KE1_OFF  + mb] = red[3][0] + red[3][1] + red[3][2] + red[3][3];
        }
    }
}

__global__ __launch_bounds__(256) void physics_finalize(
    const float* __restrict__ ws, float* __restrict__ out)
{
    __shared__ float redP[4], redM[4];
    const int tid = threadIdx.x, lane = tid & 63, wv = tid >> 6;

    float p = 0.f;
    for (int i = tid; i < PEN_BLOCKS; i += 256) p += ws[i];

    // wave wv reduces misc segment wv: 0=work, 1=stab, 2=ke0, 3=ke1 (segments 160 apart)
    const int base = WORK_OFF + 160 * wv;
    float m = ws[base + lane] + ws[base + 64 + lane]
            + (lane < 32 ? ws[base + 128 + lane] : 0.f);

    p = wave_sum(p);
    m = wave_sum(m);
    if (lane == 0) { redP[wv] = p; redM[wv] = m; }
    __syncthreads();

    if (tid == 0) {
        const float pen = redP[0] + redP[1] + redP[2] + redP[3];
        const float wk = redM[0], st = redM[1], k0 = redM[2], k1 = redM[3];
        const float pen_loss  = pen / (float)((long long)B * T * (N * (N - 1) / 2));
        const float stab_loss = st / (float)STAB_N;
        const float ke_s = 0.5f * k0 / (float)(B * N);
        const float ke_e = 0.5f * k1 / (float)(B * N);
        const float work = wk / (float)WORK_N;
        out[0] = 10.0f * pen_loss + stab_loss + 0.1f * fabsf(ke_e - ke_s - work);
    }
}

extern "C" void kernel_launch(void* const* d_in, const int* in_sizes, int n_in,
                              void* d_out, int out_size, void* d_ws, size_t ws_size,
                              hipStream_t stream) {
    const float* traj = (const float*)d_in[0];
    const float* vel  = (const float*)d_in[1];
    const float* frc  = (const float*)d_in[2];
    float* out = (float*)d_out;
    float* ws  = (float*)d_ws;

    physics_fused<<<TOTAL_BLOCKS, THREADS, 0, stream>>>(traj, vel, frc, ws);
    physics_finalize<<<1, 256, 0, stream>>>(ws, out);
}